// Round 2
// baseline (2677.828 us; speedup 1.0000x reference)
//
#include <hip/hip_runtime.h>

#define NODE_D 128
#define NUM_GRAPHS 64

// ---------------------------------------------------------------------------
// Scatter: agg[dst] += X[src]  (+ cnt[dst] += 1 when cnt != nullptr)
// 8 edges per 256-thread block; 32 lanes x float4 per edge.
// ---------------------------------------------------------------------------
__global__ __launch_bounds__(256) void k_scatter(
    const float* __restrict__ X, const int* __restrict__ src,
    const int* __restrict__ dst, float* agg, float* cnt, int E)
{
    int e = blockIdx.x * 8 + (threadIdx.x >> 5);
    if (e >= E) return;
    int lane = threadIdx.x & 31;
    int s = src[e];
    int d = dst[e];
    float4 v = *(const float4*)(X + (size_t)s * NODE_D + lane * 4);
    float* a = agg + (size_t)d * NODE_D + lane * 4;
    atomicAdd(a + 0, v.x);
    atomicAdd(a + 1, v.y);
    atomicAdd(a + 2, v.z);
    atomicAdd(a + 3, v.w);
    if (cnt != nullptr && lane == 0) atomicAdd(cnt + d, 1.0f);
}

// ---------------------------------------------------------------------------
// Normalize: agg[i][:] *= 1/max(cnt[i],1)
// ---------------------------------------------------------------------------
__global__ __launch_bounds__(256) void k_normalize(
    float* agg, const float* __restrict__ cnt, int N)
{
    int idx = blockIdx.x * 256 + threadIdx.x;   // over N*32 float4s
    int i  = idx >> 5;
    int k4 = idx & 31;
    if (i >= N) return;
    float r = 1.0f / fmaxf(cnt[i], 1.0f);
    float4* p = (float4*)(agg + (size_t)i * NODE_D + k4 * 4);
    float4 v = *p;
    v.x *= r; v.y *= r; v.z *= r; v.w *= r;
    *p = v;
}

// ---------------------------------------------------------------------------
// Fused SAGE GEMM: out = maybe_relu([A0 || A1] @ [Wl ; Wr] + bias)
// Combined K = 256. Block: 64 rows x 128 cols, 256 threads.
// Thread: 8 rows x 4 cols. LDS: Wc[64][128] (32KB) + Ax[64][68] (17KB).
// NOTE: out may alias A0 (in-place): each block writes only its own rows, and
// all A0 reads (staging) precede the epilogue store. No __restrict__ on those.
// ---------------------------------------------------------------------------
#define BM 64
#define KC 64
#define SK (KC + 4)

__global__ __launch_bounds__(256) void k_gemm(
    const float* A0,                 // [N][128] normalized aggregate
    const float* __restrict__ A1,    // [N][128] x or h
    const float* __restrict__ Wl,    // [128][128]
    const float* __restrict__ Wr,    // [128][128]
    const float* __restrict__ bias,  // [128]
    float* out,                      // [N][128]
    int N, int do_relu)
{
    __shared__ float Wc[KC][128];
    __shared__ float Ax[BM][SK];

    const int t    = threadIdx.x;
    const int row0 = blockIdx.x * BM;
    const int colt = (t & 31) * 4;   // 0..124
    const int rg   = t >> 5;         // 0..7 -> rows rg*8 .. rg*8+7

    float4 acc[8];
    float4 bv = *(const float4*)(bias + colt);
#pragma unroll
    for (int r = 0; r < 8; ++r) acc[r] = bv;

    for (int kc = 0; kc < 2 * NODE_D; kc += KC) {
        // ---- stage W chunk: KC x 128 floats = 2048 float4, 8 per thread
        const float* Wsrc = (kc < NODE_D) ? (Wl + (size_t)kc * NODE_D)
                                          : (Wr + (size_t)(kc - NODE_D) * NODE_D);
#pragma unroll
        for (int i = 0; i < 8; ++i) {
            int fi = i * 256 + t;        // 0..2047
            int kk = fi >> 5;            // 0..63
            int j4 = fi & 31;            // 0..31
            float4 v = *(const float4*)(Wsrc + kk * NODE_D + j4 * 4);
            *(float4*)(&Wc[kk][j4 * 4]) = v;
        }
        // ---- stage A chunk: BM x KC floats = 1024 float4, 4 per thread
#pragma unroll
        for (int i = 0; i < 4; ++i) {
            int fi = i * 256 + t;        // 0..1023
            int r  = fi >> 4;            // 0..63
            int k4 = fi & 15;            // 0..15
            int row = row0 + r;
            int k   = kc + k4 * 4;       // combined-k
            float4 v = make_float4(0.f, 0.f, 0.f, 0.f);
            if (row < N) {
                const float* srcp = (k < NODE_D)
                    ? (A0 + (size_t)row * NODE_D + k)
                    : (A1 + (size_t)row * NODE_D + (k - NODE_D));
                v = *(const float4*)srcp;
            }
            *(float4*)(&Ax[r][k4 * 4]) = v;
        }
        __syncthreads();
        // ---- compute
#pragma unroll
        for (int kk = 0; kk < KC; kk += 4) {
            float4 w0 = *(const float4*)(&Wc[kk + 0][colt]);
            float4 w1 = *(const float4*)(&Wc[kk + 1][colt]);
            float4 w2 = *(const float4*)(&Wc[kk + 2][colt]);
            float4 w3 = *(const float4*)(&Wc[kk + 3][colt]);
#pragma unroll
            for (int r = 0; r < 8; ++r) {
                float4 a = *(const float4*)(&Ax[rg * 8 + r][kk]);
                acc[r].x += a.x * w0.x + a.y * w1.x + a.z * w2.x + a.w * w3.x;
                acc[r].y += a.x * w0.y + a.y * w1.y + a.z * w2.y + a.w * w3.y;
                acc[r].z += a.x * w0.z + a.y * w1.z + a.z * w2.z + a.w * w3.z;
                acc[r].w += a.x * w0.w + a.y * w1.w + a.z * w2.w + a.w * w3.w;
            }
        }
        __syncthreads();
    }
    // ---- epilogue
#pragma unroll
    for (int r = 0; r < 8; ++r) {
        int row = row0 + rg * 8 + r;
        if (row < N) {
            float4 v = acc[r];
            if (do_relu) {
                v.x = fmaxf(v.x, 0.f); v.y = fmaxf(v.y, 0.f);
                v.z = fmaxf(v.z, 0.f); v.w = fmaxf(v.w, 0.f);
            }
            *(float4*)(out + (size_t)row * NODE_D + colt) = v;
        }
    }
}

// ---------------------------------------------------------------------------
// Global mean pool, phase 1: segment-sum by (sorted) batch id.
// Block processes 256 rows; 2 row-lanes x 128 cols. Running sum flushed at
// segment boundaries -> few atomics.
// ---------------------------------------------------------------------------
#define PR 256
__global__ __launch_bounds__(256) void k_pool(
    const float* __restrict__ Y, const int* __restrict__ batch,
    float* gsum, float* gcnt, int N)
{
    int col  = threadIdx.x & 127;
    int half = threadIdx.x >> 7;
    int r0   = blockIdx.x * PR;
    int rend = min(r0 + PR, N);
    float run = 0.f, rcount = 0.f;
    int cur = -1;
    for (int r = r0 + half; r < rend; r += 2) {
        int g = batch[r];
        if (g != cur) {
            if (cur >= 0) {
                atomicAdd(&gsum[cur * NODE_D + col], run);
                if (col == 0) atomicAdd(&gcnt[cur], rcount);
            }
            cur = g; run = 0.f; rcount = 0.f;
        }
        run    += Y[(size_t)r * NODE_D + col];
        rcount += 1.0f;
    }
    if (cur >= 0) {
        atomicAdd(&gsum[cur * NODE_D + col], run);
        if (col == 0) atomicAdd(&gcnt[cur], rcount);
    }
}

// ---------------------------------------------------------------------------
// Pool phase 2: out[g][j] = gsum[g][j] / max(gcnt[g],1)
// ---------------------------------------------------------------------------
__global__ __launch_bounds__(256) void k_finalize(
    const float* __restrict__ gsum, const float* __restrict__ gcnt, float* out)
{
    int idx = blockIdx.x * 256 + threadIdx.x;   // 0..8191
    int g = idx >> 7;
    out[idx] = gsum[idx] / fmaxf(gcnt[g], 1.0f);
}

// ---------------------------------------------------------------------------
extern "C" void kernel_launch(void* const* d_in, const int* in_sizes, int n_in,
                              void* d_out, int out_size, void* d_ws, size_t ws_size,
                              hipStream_t stream)
{
    const float* x   = (const float*)d_in[0];
    const int*   ei  = (const int*)d_in[1];
    const int*   bat = (const int*)d_in[2];
    const float* W1l = (const float*)d_in[3];
    const float* b1  = (const float*)d_in[4];
    const float* W1r = (const float*)d_in[5];
    const float* W2l = (const float*)d_in[6];
    const float* b2  = (const float*)d_in[7];
    const float* W2r = (const float*)d_in[8];

    const int N = in_sizes[0] / NODE_D;
    const int E = in_sizes[1] / 2;
    const int* srcp = ei;
    const int* dstp = ei + E;

    // workspace: P [N][128], Q [N][128], cnt [N], gsum [64][128], gcnt [64]
    float* P    = (float*)d_ws;
    float* Q    = P + (size_t)N * NODE_D;
    float* cnt  = Q + (size_t)N * NODE_D;
    float* gsum = cnt + N;
    float* gcnt = gsum + NUM_GRAPHS * NODE_D;

    hipMemsetAsync(P,   0, (size_t)N * NODE_D * sizeof(float), stream);
    hipMemsetAsync(cnt, 0, (size_t)N * sizeof(float), stream);
    hipMemsetAsync(gsum, 0, (NUM_GRAPHS * NODE_D + NUM_GRAPHS) * sizeof(float), stream);

    // ---- layer 1: agg1 -> P
    k_scatter<<<(E + 7) / 8, 256, 0, stream>>>(x, srcp, dstp, P, cnt, E);
    k_normalize<<<(N * 32 + 255) / 256, 256, 0, stream>>>(P, cnt, N);
    k_gemm<<<(N + BM - 1) / BM, 256, 0, stream>>>(P, x, W1l, W1r, b1, Q, N, 1);

    // ---- layer 2: agg2 -> P (reuse), y -> P in-place
    hipMemsetAsync(P, 0, (size_t)N * NODE_D * sizeof(float), stream);
    k_scatter<<<(E + 7) / 8, 256, 0, stream>>>(Q, srcp, dstp, P, nullptr, E);
    k_normalize<<<(N * 32 + 255) / 256, 256, 0, stream>>>(P, cnt, N);
    k_gemm<<<(N + BM - 1) / BM, 256, 0, stream>>>(P, Q, W2l, W2r, b2, P, N, 0);

    // ---- global mean pool
    k_pool<<<(N + PR - 1) / PR, 256, 0, stream>>>(P, bat, gsum, gcnt, N);
    k_finalize<<<(NUM_GRAPHS * NODE_D) / 256, 256, 0, stream>>>(gsum, gcnt, (float*)d_out);
}

// Round 4
// 746.834 us; speedup vs baseline: 3.5856x; 3.5856x over previous
//
#include <hip/hip_runtime.h>

#define NODE_D 128
#define NUM_GRAPHS 64
#define SCHUNK 2048   // elements per scan block (256 thr x 8)

// ---------------------------------------------------------------------------
// CSR build, step 1: degree histogram (int atomics — cheap)
// ---------------------------------------------------------------------------
__global__ __launch_bounds__(256) void k_hist(
    const int* __restrict__ dst, int* deg, int E)
{
    int e = blockIdx.x * 256 + threadIdx.x;
    if (e < E) atomicAdd(&deg[dst[e]], 1);
}

// ---------------------------------------------------------------------------
// CSR build, step 2a: per-block partial sums of deg
// ---------------------------------------------------------------------------
__global__ __launch_bounds__(256) void k_scan_partial(
    const int* __restrict__ deg, int* partial, int N)
{
    __shared__ int sbuf[256];
    int base = blockIdx.x * SCHUNK;
    int t = threadIdx.x;
    int s = 0;
#pragma unroll
    for (int i = 0; i < 8; ++i) {
        int idx = base + i * 256 + t;
        if (idx < N) s += deg[idx];
    }
    sbuf[t] = s;
    __syncthreads();
    for (int off = 128; off > 0; off >>= 1) {
        if (t < off) sbuf[t] += sbuf[t + off];
        __syncthreads();
    }
    if (t == 0) partial[blockIdx.x] = sbuf[0];
}

// ---------------------------------------------------------------------------
// CSR build, step 2b: serial exclusive scan of block partials (nb ~ 49)
// ---------------------------------------------------------------------------
__global__ void k_scan_top(int* partial, int nb)
{
    if (threadIdx.x == 0 && blockIdx.x == 0) {
        int run = 0;
        for (int i = 0; i < nb; ++i) { int v = partial[i]; partial[i] = run; run += v; }
    }
}

// ---------------------------------------------------------------------------
// CSR build, step 2c: per-block exclusive scan -> offs, cursor
// ---------------------------------------------------------------------------
__global__ __launch_bounds__(256) void k_scan_final(
    const int* __restrict__ deg, const int* __restrict__ partial,
    int* offs, int* cursor, int N)
{
    __shared__ int sbuf[256];
    int base = blockIdx.x * SCHUNK;
    int t = threadIdx.x;
    int idx0 = base + t * 8;
    int loc[8];
    int s = 0;
#pragma unroll
    for (int i = 0; i < 8; ++i) {
        int idx = idx0 + i;
        int v = (idx < N) ? deg[idx] : 0;
        loc[i] = s;
        s += v;
    }
    sbuf[t] = s;
    __syncthreads();
    // Hillis-Steele inclusive scan over 256 thread sums
    for (int off = 1; off < 256; off <<= 1) {
        int tmp = (t >= off) ? sbuf[t - off] : 0;
        __syncthreads();
        sbuf[t] += tmp;
        __syncthreads();
    }
    int pre = sbuf[t] - s + partial[blockIdx.x];   // exclusive prefix for this thread
#pragma unroll
    for (int i = 0; i < 8; ++i) {
        int idx = idx0 + i;
        if (idx < N) {
            int v = pre + loc[i];
            offs[idx]   = v;
            cursor[idx] = v;
        }
    }
}

// ---------------------------------------------------------------------------
// CSR build, step 3: bucket src ids into CSR order
// ---------------------------------------------------------------------------
__global__ __launch_bounds__(256) void k_fill(
    const int* __restrict__ src, const int* __restrict__ dst,
    int* cursor, int* srcs, int E)
{
    int e = blockIdx.x * 256 + threadIdx.x;
    if (e < E) {
        int pos = atomicAdd(&cursor[dst[e]], 1);
        srcs[pos] = src[e];
    }
}

// ---------------------------------------------------------------------------
// Pull-aggregate + mean: out[i] = (1/max(deg_i,1)) * sum_{j in N(i)} X[j]
// 32 lanes x float4 per node, 8 nodes per 256-thread block. No atomics.
// ---------------------------------------------------------------------------
__global__ __launch_bounds__(256) void k_gather(
    const float* __restrict__ X, const int* __restrict__ srcs,
    const int* __restrict__ offs, const int* __restrict__ deg,
    float* __restrict__ out, int N)
{
    int node = blockIdx.x * 8 + (threadIdx.x >> 5);
    if (node >= N) return;
    int lane  = threadIdx.x & 31;
    int start = offs[node];
    int d     = deg[node];
    float4 acc = make_float4(0.f, 0.f, 0.f, 0.f);
    for (int j = 0; j < d; ++j) {
        int s = srcs[start + j];
        float4 v = *(const float4*)(X + (size_t)s * NODE_D + lane * 4);
        acc.x += v.x; acc.y += v.y; acc.z += v.z; acc.w += v.w;
    }
    float r = 1.0f / fmaxf((float)d, 1.0f);
    acc.x *= r; acc.y *= r; acc.z *= r; acc.w *= r;
    *(float4*)(out + (size_t)node * NODE_D + lane * 4) = acc;
}

// ---------------------------------------------------------------------------
// Fused SAGE GEMM: out = maybe_relu([A0 || A1] @ [Wl ; Wr] + bias)
// Combined K = 256. Block: 64 rows x 128 cols, 256 threads.
// NOTE: out may alias A0 (in-place): each block writes only its own rows, and
// all A0 reads (staging) precede the epilogue store. No __restrict__ on those.
// ---------------------------------------------------------------------------
#define BM 64
#define KC 64
#define SK (KC + 4)

__global__ __launch_bounds__(256) void k_gemm(
    const float* A0,                 // [N][128] normalized aggregate
    const float* __restrict__ A1,    // [N][128] x or h
    const float* __restrict__ Wl,    // [128][128]
    const float* __restrict__ Wr,    // [128][128]
    const float* __restrict__ bias,  // [128]
    float* out,                      // [N][128]
    int N, int do_relu)
{
    __shared__ float Wc[KC][128];
    __shared__ float Ax[BM][SK];

    const int t    = threadIdx.x;
    const int row0 = blockIdx.x * BM;
    const int colt = (t & 31) * 4;   // 0..124
    const int rg   = t >> 5;         // 0..7 -> rows rg*8 .. rg*8+7

    float4 acc[8];
    float4 bv = *(const float4*)(bias + colt);
#pragma unroll
    for (int r = 0; r < 8; ++r) acc[r] = bv;

    for (int kc = 0; kc < 2 * NODE_D; kc += KC) {
        // ---- stage W chunk: KC x 128 floats = 2048 float4, 8 per thread
        const float* Wsrc = (kc < NODE_D) ? (Wl + (size_t)kc * NODE_D)
                                          : (Wr + (size_t)(kc - NODE_D) * NODE_D);
#pragma unroll
        for (int i = 0; i < 8; ++i) {
            int fi = i * 256 + t;        // 0..2047
            int kk = fi >> 5;            // 0..63
            int j4 = fi & 31;            // 0..31
            float4 v = *(const float4*)(Wsrc + kk * NODE_D + j4 * 4);
            *(float4*)(&Wc[kk][j4 * 4]) = v;
        }
        // ---- stage A chunk: BM x KC floats = 1024 float4, 4 per thread
#pragma unroll
        for (int i = 0; i < 4; ++i) {
            int fi = i * 256 + t;        // 0..1023
            int r  = fi >> 4;            // 0..63
            int k4 = fi & 15;            // 0..15
            int row = row0 + r;
            int k   = kc + k4 * 4;       // combined-k
            float4 v = make_float4(0.f, 0.f, 0.f, 0.f);
            if (row < N) {
                const float* srcp = (k < NODE_D)
                    ? (A0 + (size_t)row * NODE_D + k)
                    : (A1 + (size_t)row * NODE_D + (k - NODE_D));
                v = *(const float4*)srcp;
            }
            *(float4*)(&Ax[r][k4 * 4]) = v;
        }
        __syncthreads();
        // ---- compute
#pragma unroll
        for (int kk = 0; kk < KC; kk += 4) {
            float4 w0 = *(const float4*)(&Wc[kk + 0][colt]);
            float4 w1 = *(const float4*)(&Wc[kk + 1][colt]);
            float4 w2 = *(const float4*)(&Wc[kk + 2][colt]);
            float4 w3 = *(const float4*)(&Wc[kk + 3][colt]);
#pragma unroll
            for (int r = 0; r < 8; ++r) {
                float4 a = *(const float4*)(&Ax[rg * 8 + r][kk]);
                acc[r].x += a.x * w0.x + a.y * w1.x + a.z * w2.x + a.w * w3.x;
                acc[r].y += a.x * w0.y + a.y * w1.y + a.z * w2.y + a.w * w3.y;
                acc[r].z += a.x * w0.z + a.y * w1.z + a.z * w2.z + a.w * w3.z;
                acc[r].w += a.x * w0.w + a.y * w1.w + a.z * w2.w + a.w * w3.w;
            }
        }
        __syncthreads();
    }
    // ---- epilogue
#pragma unroll
    for (int r = 0; r < 8; ++r) {
        int row = row0 + rg * 8 + r;
        if (row < N) {
            float4 v = acc[r];
            if (do_relu) {
                v.x = fmaxf(v.x, 0.f); v.y = fmaxf(v.y, 0.f);
                v.z = fmaxf(v.z, 0.f); v.w = fmaxf(v.w, 0.f);
            }
            *(float4*)(out + (size_t)row * NODE_D + colt) = v;
        }
    }
}

// ---------------------------------------------------------------------------
// Global mean pool, phase 1: segment-sum by (sorted) batch id.
// ---------------------------------------------------------------------------
#define PR 256
__global__ __launch_bounds__(256) void k_pool(
    const float* __restrict__ Y, const int* __restrict__ batch,
    float* gsum, float* gcnt, int N)
{
    int col  = threadIdx.x & 127;
    int half = threadIdx.x >> 7;
    int r0   = blockIdx.x * PR;
    int rend = min(r0 + PR, N);
    float run = 0.f, rcount = 0.f;
    int cur = -1;
    for (int r = r0 + half; r < rend; r += 2) {
        int g = batch[r];
        if (g != cur) {
            if (cur >= 0) {
                atomicAdd(&gsum[cur * NODE_D + col], run);
                if (col == 0) atomicAdd(&gcnt[cur], rcount);
            }
            cur = g; run = 0.f; rcount = 0.f;
        }
        run    += Y[(size_t)r * NODE_D + col];
        rcount += 1.0f;
    }
    if (cur >= 0) {
        atomicAdd(&gsum[cur * NODE_D + col], run);
        if (col == 0) atomicAdd(&gcnt[cur], rcount);
    }
}

// ---------------------------------------------------------------------------
// Pool phase 2: out[g][j] = gsum[g][j] / max(gcnt[g],1)
// ---------------------------------------------------------------------------
__global__ __launch_bounds__(256) void k_finalize(
    const float* __restrict__ gsum, const float* __restrict__ gcnt, float* out)
{
    int idx = blockIdx.x * 256 + threadIdx.x;   // 0..8191
    int g = idx >> 7;
    out[idx] = gsum[idx] / fmaxf(gcnt[g], 1.0f);
}

// ---------------------------------------------------------------------------
extern "C" void kernel_launch(void* const* d_in, const int* in_sizes, int n_in,
                              void* d_out, int out_size, void* d_ws, size_t ws_size,
                              hipStream_t stream)
{
    const float* x   = (const float*)d_in[0];
    const int*   ei  = (const int*)d_in[1];
    const int*   bat = (const int*)d_in[2];
    const float* W1l = (const float*)d_in[3];
    const float* b1  = (const float*)d_in[4];
    const float* W1r = (const float*)d_in[5];
    const float* W2l = (const float*)d_in[6];
    const float* b2  = (const float*)d_in[7];
    const float* W2r = (const float*)d_in[8];

    const int N = in_sizes[0] / NODE_D;
    const int E = in_sizes[1] / 2;
    const int* srcp = ei;
    const int* dstp = ei + E;
    const int nb = (N + SCHUNK - 1) / SCHUNK;

    // workspace layout (floats first, then ints)
    float* P    = (float*)d_ws;                       // [N][128]
    float* Q    = P + (size_t)N * NODE_D;             // [N][128]
    float* gsum = Q + (size_t)N * NODE_D;             // [64][128]
    float* gcnt = gsum + NUM_GRAPHS * NODE_D;         // [64]
    int* deg     = (int*)(gcnt + NUM_GRAPHS);         // [N]
    int* offs    = deg + N;                           // [N]
    int* cursor  = offs + N;                          // [N]
    int* partial = cursor + N;                        // [nb]
    int* srcs    = partial + ((nb + 63) & ~63);       // [E]

    hipMemsetAsync(deg, 0, (size_t)N * sizeof(int), stream);
    hipMemsetAsync(gsum, 0, (NUM_GRAPHS * NODE_D + NUM_GRAPHS) * sizeof(float), stream);

    // ---- CSR build (once; shared by both layers)
    k_hist<<<(E + 255) / 256, 256, 0, stream>>>(dstp, deg, E);
    k_scan_partial<<<nb, 256, 0, stream>>>(deg, partial, N);
    k_scan_top<<<1, 64, 0, stream>>>(partial, nb);
    k_scan_final<<<nb, 256, 0, stream>>>(deg, partial, offs, cursor, N);
    k_fill<<<(E + 255) / 256, 256, 0, stream>>>(srcp, dstp, cursor, srcs, E);

    // ---- layer 1: mean-agg -> P, then h = relu([P||x]W) -> Q
    k_gather<<<(N + 7) / 8, 256, 0, stream>>>(x, srcs, offs, deg, P, N);
    k_gemm<<<(N + BM - 1) / BM, 256, 0, stream>>>(P, x, W1l, W1r, b1, Q, N, 1);

    // ---- layer 2: mean-agg(Q) -> P, then y = [P||Q]W -> P (in-place)
    k_gather<<<(N + 7) / 8, 256, 0, stream>>>(Q, srcs, offs, deg, P, N);
    k_gemm<<<(N + BM - 1) / BM, 256, 0, stream>>>(P, Q, W2l, W2r, b2, P, N, 0);

    // ---- global mean pool
    k_pool<<<(N + PR - 1) / PR, 256, 0, stream>>>(P, bat, gsum, gcnt, N);
    k_finalize<<<(NUM_GRAPHS * NODE_D) / 256, 256, 0, stream>>>(gsum, gcnt, (float*)d_out);
}

// Round 6
// 402.981 us; speedup vs baseline: 6.6450x; 1.8533x over previous
//
#include <hip/hip_runtime.h>

#define NODE_D 128
#define NUM_GRAPHS 64
#define SCHUNK 2048   // elements per scan block (256 thr x 8)

typedef __bf16 v8bf __attribute__((ext_vector_type(8)));
typedef __bf16 v4bf __attribute__((ext_vector_type(4)));
typedef float  v4f  __attribute__((ext_vector_type(4)));

// ---------------------------------------------------------------------------
// CSR build, step 1: degree histogram (int atomics — cheap)
// ---------------------------------------------------------------------------
__global__ __launch_bounds__(256) void k_hist(
    const int* __restrict__ dst, int* deg, int E)
{
    int e = blockIdx.x * 256 + threadIdx.x;
    if (e < E) atomicAdd(&deg[dst[e]], 1);
}

// ---------------------------------------------------------------------------
// CSR build, step 2a: per-block partial sums of deg
// ---------------------------------------------------------------------------
__global__ __launch_bounds__(256) void k_scan_partial(
    const int* __restrict__ deg, int* partial, int N)
{
    __shared__ int sbuf[256];
    int base = blockIdx.x * SCHUNK;
    int t = threadIdx.x;
    int s = 0;
#pragma unroll
    for (int i = 0; i < 8; ++i) {
        int idx = base + i * 256 + t;
        if (idx < N) s += deg[idx];
    }
    sbuf[t] = s;
    __syncthreads();
    for (int off = 128; off > 0; off >>= 1) {
        if (t < off) sbuf[t] += sbuf[t + off];
        __syncthreads();
    }
    if (t == 0) partial[blockIdx.x] = sbuf[0];
}

// ---------------------------------------------------------------------------
// CSR build, step 2b: serial exclusive scan of block partials (nb ~ 49)
// ---------------------------------------------------------------------------
__global__ void k_scan_top(int* partial, int nb)
{
    if (threadIdx.x == 0 && blockIdx.x == 0) {
        int run = 0;
        for (int i = 0; i < nb; ++i) { int v = partial[i]; partial[i] = run; run += v; }
    }
}

// ---------------------------------------------------------------------------
// CSR build, step 2c: per-block exclusive scan -> offs, cursor
// ---------------------------------------------------------------------------
__global__ __launch_bounds__(256) void k_scan_final(
    const int* __restrict__ deg, const int* __restrict__ partial,
    int* offs, int* cursor, int N)
{
    __shared__ int sbuf[256];
    int base = blockIdx.x * SCHUNK;
    int t = threadIdx.x;
    int idx0 = base + t * 8;
    int loc[8];
    int s = 0;
#pragma unroll
    for (int i = 0; i < 8; ++i) {
        int idx = idx0 + i;
        int v = (idx < N) ? deg[idx] : 0;
        loc[i] = s;
        s += v;
    }
    sbuf[t] = s;
    __syncthreads();
    for (int off = 1; off < 256; off <<= 1) {
        int tmp = (t >= off) ? sbuf[t - off] : 0;
        __syncthreads();
        sbuf[t] += tmp;
        __syncthreads();
    }
    int pre = sbuf[t] - s + partial[blockIdx.x];
#pragma unroll
    for (int i = 0; i < 8; ++i) {
        int idx = idx0 + i;
        if (idx < N) {
            int v = pre + loc[i];
            offs[idx]   = v;
            cursor[idx] = v;
        }
    }
}

// ---------------------------------------------------------------------------
// CSR build, step 3: bucket src ids into CSR order
// ---------------------------------------------------------------------------
__global__ __launch_bounds__(256) void k_fill(
    const int* __restrict__ src, const int* __restrict__ dst,
    int* cursor, int* srcs, int E)
{
    int e = blockIdx.x * 256 + threadIdx.x;
    if (e < E) {
        int pos = atomicAdd(&cursor[dst[e]], 1);
        srcs[pos] = src[e];
    }
}

// ---------------------------------------------------------------------------
// Weight prep: Wt[c][k] = bf16( k<128 ? Wl[k][c] : Wr[k-128][c] )
// Writes coalesced (k fast); reads L2-resident. 32768 elements per layer.
// ---------------------------------------------------------------------------
__global__ __launch_bounds__(256) void k_prep(
    const float* __restrict__ Wl, const float* __restrict__ Wr,
    unsigned short* __restrict__ Wt)
{
    int idx = blockIdx.x * 256 + threadIdx.x;   // 0..32767
    int k = idx & 255;
    int c = idx >> 8;
    float v = (k < 128) ? Wl[k * 128 + c] : Wr[(k - 128) * 128 + c];
    __bf16 b = (__bf16)v;
    Wt[c * 256 + k] = __builtin_bit_cast(unsigned short, b);
}

// ---------------------------------------------------------------------------
// Pull-aggregate + mean: out[i] = (1/max(deg_i,1)) * sum_{j in N(i)} X[j]
// ---------------------------------------------------------------------------
__global__ __launch_bounds__(256) void k_gather(
    const float* __restrict__ X, const int* __restrict__ srcs,
    const int* __restrict__ offs, const int* __restrict__ deg,
    float* __restrict__ out, int N)
{
    int node = blockIdx.x * 8 + (threadIdx.x >> 5);
    if (node >= N) return;
    int lane  = threadIdx.x & 31;
    int start = offs[node];
    int d     = deg[node];
    float4 acc = make_float4(0.f, 0.f, 0.f, 0.f);
    for (int j = 0; j < d; ++j) {
        int s = srcs[start + j];
        float4 v = *(const float4*)(X + (size_t)s * NODE_D + lane * 4);
        acc.x += v.x; acc.y += v.y; acc.z += v.z; acc.w += v.w;
    }
    float r = 1.0f / fmaxf((float)d, 1.0f);
    acc.x *= r; acc.y *= r; acc.z *= r; acc.w *= r;
    *(float4*)(out + (size_t)node * NODE_D + lane * 4) = acc;
}

// ---------------------------------------------------------------------------
// MFMA SAGE GEMM: out = maybe_relu([A0 || A1] @ W + bias), W given as
// Wt bf16 [128 cols][256 k] (transposed). Block: 128 rows x 128 cols,
// 256 threads = 4 waves, each wave 32 rows. K chunked by 64.
// A converted fp32->bf16 during staging. mfma_f32_16x16x32_bf16.
// Frag layouts: A row=lane&15, k=(lane>>4)*8+j (contiguous 8);
//               B col=lane&15, same k;  C/D col=lane&15, row=(lane>>4)*4+reg.
// In-place safe (out may alias A0): block reads only its own 128 rows during
// staging; epilogue stores after all staging. LDS 2x128x72 bf16 = 36.9 KB.
// ---------------------------------------------------------------------------
#define GROWS 128
#define GKC   64
#define GSTR  (GKC + 8)   // 72 bf16 -> 144B row stride, <=2-way bank aliasing

__global__ __launch_bounds__(256) void k_gemm_mfma(
    const float* A0,                          // [N][128] aggregate (may alias out)
    const float* __restrict__ A1,             // [N][128] x or h
    const unsigned short* __restrict__ Wt,    // [128][256] bf16 bits
    const float* __restrict__ bias,           // [128] fp32
    float* out, int N, int do_relu)
{
    __shared__ __bf16 sA[GROWS][GSTR];
    __shared__ __bf16 sW[GROWS][GSTR];

    const int t    = threadIdx.x;
    const int wave = t >> 6;          // 0..3
    const int lane = t & 63;
    const int l15  = lane & 15;
    const int lg   = lane >> 4;       // 0..3
    const int row0 = blockIdx.x * GROWS;

    v4f acc[2][8];
#pragma unroll
    for (int m = 0; m < 2; ++m)
#pragma unroll
        for (int n = 0; n < 8; ++n)
            acc[m][n] = (v4f){0.f, 0.f, 0.f, 0.f};

    float bk[8];
#pragma unroll
    for (int n = 0; n < 8; ++n) bk[n] = bias[n * 16 + l15];

    for (int kc = 0; kc < 4; ++kc) {
        const int kbase = kc * GKC;                       // 0,64,128,192
        const float* Asrc = (kbase < NODE_D) ? A0 : A1;
        const int koff = kbase & (NODE_D - 1);            // 0 or 64
        // ---- stage A chunk: 128 rows x 64 k fp32 -> bf16. 8 float4/thread.
#pragma unroll
        for (int i = 0; i < 8; ++i) {
            int fi = i * 256 + t;     // 0..2047
            int r  = fi >> 4;         // 0..127
            int k4 = fi & 15;         // 0..15
            int row = row0 + r;
            float4 v = make_float4(0.f, 0.f, 0.f, 0.f);
            if (row < N) v = *(const float4*)(Asrc + (size_t)row * NODE_D + koff + k4 * 4);
            v4bf b;
            b[0] = (__bf16)v.x; b[1] = (__bf16)v.y;
            b[2] = (__bf16)v.z; b[3] = (__bf16)v.w;
            *(v4bf*)&sA[r][k4 * 4] = b;
        }
        // ---- stage W chunk: 128 cols x 64 k bf16. 4 x bf16x8 per thread.
#pragma unroll
        for (int i = 0; i < 4; ++i) {
            int fi = i * 256 + t;     // 0..1023
            int c  = fi >> 3;         // 0..127
            int k8 = fi & 7;          // 0..7
            v8bf w = *(const v8bf*)((const __bf16*)Wt + c * 256 + kbase + k8 * 8);
            *(v8bf*)&sW[c][k8 * 8] = w;
        }
        __syncthreads();
        // ---- compute: 2 k-steps of 32
#pragma unroll
        for (int ks = 0; ks < 2; ++ks) {
            const int kk = ks * 32 + lg * 8;
            v8bf a0 = *(const v8bf*)&sA[wave * 32 +  0 + l15][kk];
            v8bf a1 = *(const v8bf*)&sA[wave * 32 + 16 + l15][kk];
#pragma unroll
            for (int n = 0; n < 8; ++n) {
                v8bf b = *(const v8bf*)&sW[n * 16 + l15][kk];
                acc[0][n] = __builtin_amdgcn_mfma_f32_16x16x32_bf16(a0, b, acc[0][n], 0, 0, 0);
                acc[1][n] = __builtin_amdgcn_mfma_f32_16x16x32_bf16(a1, b, acc[1][n], 0, 0, 0);
            }
        }
        __syncthreads();
    }
    // ---- epilogue: bias + optional relu, fp32 stores
#pragma unroll
    for (int m = 0; m < 2; ++m) {
#pragma unroll
        for (int rr = 0; rr < 4; ++rr) {
            int row = row0 + wave * 32 + m * 16 + lg * 4 + rr;
            if (row < N) {
#pragma unroll
                for (int n = 0; n < 8; ++n) {
                    float v = acc[m][n][rr] + bk[n];
                    if (do_relu) v = fmaxf(v, 0.f);
                    out[(size_t)row * NODE_D + n * 16 + l15] = v;
                }
            }
        }
    }
}

// ---------------------------------------------------------------------------
// Global mean pool, phase 1: segment-sum by (sorted) batch id.
// ---------------------------------------------------------------------------
#define PR 256
__global__ __launch_bounds__(256) void k_pool(
    const float* __restrict__ Y, const int* __restrict__ batch,
    float* gsum, float* gcnt, int N)
{
    int col  = threadIdx.x & 127;
    int half = threadIdx.x >> 7;
    int r0   = blockIdx.x * PR;
    int rend = min(r0 + PR, N);
    float run = 0.f, rcount = 0.f;
    int cur = -1;
    for (int r = r0 + half; r < rend; r += 2) {
        int g = batch[r];
        if (g != cur) {
            if (cur >= 0) {
                atomicAdd(&gsum[cur * NODE_D + col], run);
                if (col == 0) atomicAdd(&gcnt[cur], rcount);
            }
            cur = g; run = 0.f; rcount = 0.f;
        }
        run    += Y[(size_t)r * NODE_D + col];
        rcount += 1.0f;
    }
    if (cur >= 0) {
        atomicAdd(&gsum[cur * NODE_D + col], run);
        if (col == 0) atomicAdd(&gcnt[cur], rcount);
    }
}

// ---------------------------------------------------------------------------
// Pool phase 2: out[g][j] = gsum[g][j] / max(gcnt[g],1)
// ---------------------------------------------------------------------------
__global__ __launch_bounds__(256) void k_finalize(
    const float* __restrict__ gsum, const float* __restrict__ gcnt, float* out)
{
    int idx = blockIdx.x * 256 + threadIdx.x;   // 0..8191
    int g = idx >> 7;
    out[idx] = gsum[idx] / fmaxf(gcnt[g], 1.0f);
}

// ---------------------------------------------------------------------------
extern "C" void kernel_launch(void* const* d_in, const int* in_sizes, int n_in,
                              void* d_out, int out_size, void* d_ws, size_t ws_size,
                              hipStream_t stream)
{
    const float* x   = (const float*)d_in[0];
    const int*   ei  = (const int*)d_in[1];
    const int*   bat = (const int*)d_in[2];
    const float* W1l = (const float*)d_in[3];
    const float* b1  = (const float*)d_in[4];
    const float* W1r = (const float*)d_in[5];
    const float* W2l = (const float*)d_in[6];
    const float* b2  = (const float*)d_in[7];
    const float* W2r = (const float*)d_in[8];

    const int N = in_sizes[0] / NODE_D;
    const int E = in_sizes[1] / 2;
    const int* srcp = ei;
    const int* dstp = ei + E;
    const int nb = (N + SCHUNK - 1) / SCHUNK;

    // workspace layout (floats first, then ints)
    float* P    = (float*)d_ws;                       // [N][128]
    float* Q    = P + (size_t)N * NODE_D;             // [N][128]
    float* gsum = Q + (size_t)N * NODE_D;             // [64][128]
    float* gcnt = gsum + NUM_GRAPHS * NODE_D;         // [64]
    int* deg     = (int*)(gcnt + NUM_GRAPHS);         // [N]
    int* offs    = deg + N;                           // [N]
    int* cursor  = offs + N;                          // [N] (dead after k_fill)
    int* partial = cursor + N;                        // [nb]
    int* srcs    = partial + ((nb + 63) & ~63);       // [E]
    // Wt1/Wt2 (32768 ushort each = 16384 int each) overlay the dead cursor
    // array (N >= 32768 ints) — written by k_prep AFTER k_fill finishes.
    unsigned short* Wt1 = (unsigned short*)cursor;
    unsigned short* Wt2 = Wt1 + 128 * 256;

    hipMemsetAsync(deg, 0, (size_t)N * sizeof(int), stream);
    hipMemsetAsync(gsum, 0, (NUM_GRAPHS * NODE_D + NUM_GRAPHS) * sizeof(float), stream);

    // ---- CSR build (once; shared by both layers)
    k_hist<<<(E + 255) / 256, 256, 0, stream>>>(dstp, deg, E);
    k_scan_partial<<<nb, 256, 0, stream>>>(deg, partial, N);
    k_scan_top<<<1, 64, 0, stream>>>(partial, nb);
    k_scan_final<<<nb, 256, 0, stream>>>(deg, partial, offs, cursor, N);
    k_fill<<<(E + 255) / 256, 256, 0, stream>>>(srcp, dstp, cursor, srcs, E);

    // ---- weight prep (after k_fill: Wt overlays cursor)
    k_prep<<<128, 256, 0, stream>>>(W1l, W1r, Wt1);
    k_prep<<<128, 256, 0, stream>>>(W2l, W2r, Wt2);

    const int gblk = (N + GROWS - 1) / GROWS;
    // ---- layer 1: mean-agg -> P, then h = relu([P||x]W1) -> Q
    k_gather<<<(N + 7) / 8, 256, 0, stream>>>(x, srcs, offs, deg, P, N);
    k_gemm_mfma<<<gblk, 256, 0, stream>>>(P, x, Wt1, b1, Q, N, 1);

    // ---- layer 2: mean-agg(Q) -> P, then y = [P||Q]W2 -> P (in-place)
    k_gather<<<(N + 7) / 8, 256, 0, stream>>>(Q, srcs, offs, deg, P, N);
    k_gemm_mfma<<<gblk, 256, 0, stream>>>(P, Q, Wt2, b2, P, N, 0);

    // ---- global mean pool
    k_pool<<<(N + PR - 1) / PR, 256, 0, stream>>>(P, bat, gsum, gcnt, N);
    k_finalize<<<(NUM_GRAPHS * NODE_D) / 256, 256, 0, stream>>>(gsum, gcnt, (float*)d_out);
}

// Round 7
// 365.882 us; speedup vs baseline: 7.3188x; 1.1014x over previous
//
#include <hip/hip_runtime.h>

#define NODE_D 128
#define NUM_GRAPHS 64
#define SCHUNK 2048   // elements per scan block (256 thr x 8)

typedef __bf16 v8bf __attribute__((ext_vector_type(8)));
typedef __bf16 v4bf __attribute__((ext_vector_type(4)));
typedef float  v4f  __attribute__((ext_vector_type(4)));

// ---------------------------------------------------------------------------
// CSR build, step 1: degree histogram (int atomics — cheap)
// ---------------------------------------------------------------------------
__global__ __launch_bounds__(256) void k_hist(
    const int* __restrict__ dst, int* deg, int E)
{
    int e = blockIdx.x * 256 + threadIdx.x;
    if (e < E) atomicAdd(&deg[dst[e]], 1);
}

// ---------------------------------------------------------------------------
// CSR build, step 2a: per-block partial sums of deg
// ---------------------------------------------------------------------------
__global__ __launch_bounds__(256) void k_scan_partial(
    const int* __restrict__ deg, int* partial, int N)
{
    __shared__ int sbuf[256];
    int base = blockIdx.x * SCHUNK;
    int t = threadIdx.x;
    int s = 0;
#pragma unroll
    for (int i = 0; i < 8; ++i) {
        int idx = base + i * 256 + t;
        if (idx < N) s += deg[idx];
    }
    sbuf[t] = s;
    __syncthreads();
    for (int off = 128; off > 0; off >>= 1) {
        if (t < off) sbuf[t] += sbuf[t + off];
        __syncthreads();
    }
    if (t == 0) partial[blockIdx.x] = sbuf[0];
}

// ---------------------------------------------------------------------------
// CSR build, step 2b: serial exclusive scan of block partials (nb ~ 49)
// ---------------------------------------------------------------------------
__global__ void k_scan_top(int* partial, int nb)
{
    if (threadIdx.x == 0 && blockIdx.x == 0) {
        int run = 0;
        for (int i = 0; i < nb; ++i) { int v = partial[i]; partial[i] = run; run += v; }
    }
}

// ---------------------------------------------------------------------------
// CSR build, step 2c: per-block exclusive scan -> offs, cursor
// ---------------------------------------------------------------------------
__global__ __launch_bounds__(256) void k_scan_final(
    const int* __restrict__ deg, const int* __restrict__ partial,
    int* offs, int* cursor, int N)
{
    __shared__ int sbuf[256];
    int base = blockIdx.x * SCHUNK;
    int t = threadIdx.x;
    int idx0 = base + t * 8;
    int loc[8];
    int s = 0;
#pragma unroll
    for (int i = 0; i < 8; ++i) {
        int idx = idx0 + i;
        int v = (idx < N) ? deg[idx] : 0;
        loc[i] = s;
        s += v;
    }
    sbuf[t] = s;
    __syncthreads();
    for (int off = 1; off < 256; off <<= 1) {
        int tmp = (t >= off) ? sbuf[t - off] : 0;
        __syncthreads();
        sbuf[t] += tmp;
        __syncthreads();
    }
    int pre = sbuf[t] - s + partial[blockIdx.x];
#pragma unroll
    for (int i = 0; i < 8; ++i) {
        int idx = idx0 + i;
        if (idx < N) {
            int v = pre + loc[i];
            offs[idx]   = v;
            cursor[idx] = v;
        }
    }
}

// ---------------------------------------------------------------------------
// CSR build, step 3: bucket src ids into CSR order
// ---------------------------------------------------------------------------
__global__ __launch_bounds__(256) void k_fill(
    const int* __restrict__ src, const int* __restrict__ dst,
    int* cursor, int* srcs, int E)
{
    int e = blockIdx.x * 256 + threadIdx.x;
    if (e < E) {
        int pos = atomicAdd(&cursor[dst[e]], 1);
        srcs[pos] = src[e];
    }
}

// ---------------------------------------------------------------------------
// Weight prep: Wt[c][k] = bf16( k<128 ? Wl[k][c] : Wr[k-128][c] )
// ---------------------------------------------------------------------------
__global__ __launch_bounds__(256) void k_prep(
    const float* __restrict__ Wl, const float* __restrict__ Wr,
    unsigned short* __restrict__ Wt)
{
    int idx = blockIdx.x * 256 + threadIdx.x;   // 0..32767
    int k = idx & 255;
    int c = idx >> 8;
    float v = (k < 128) ? Wl[k * 128 + c] : Wr[(k - 128) * 128 + c];
    __bf16 b = (__bf16)v;
    Wt[c * 256 + k] = __builtin_bit_cast(unsigned short, b);
}

// ---------------------------------------------------------------------------
// Feature prep: xb = bf16(x), vectorized 8 elems/thread
// ---------------------------------------------------------------------------
__global__ __launch_bounds__(256) void k_prep_x(
    const float* __restrict__ x, unsigned short* __restrict__ xb, long n8)
{
    long idx = (long)blockIdx.x * 256 + threadIdx.x;   // over n8 = N*128/8
    if (idx >= n8) return;
    const float* p = x + idx * 8;
    float4 v0 = *(const float4*)p;
    float4 v1 = *(const float4*)(p + 4);
    v8bf b;
    b[0] = (__bf16)v0.x; b[1] = (__bf16)v0.y; b[2] = (__bf16)v0.z; b[3] = (__bf16)v0.w;
    b[4] = (__bf16)v1.x; b[5] = (__bf16)v1.y; b[6] = (__bf16)v1.z; b[7] = (__bf16)v1.w;
    *(v8bf*)(xb + idx * 8) = b;
}

// ---------------------------------------------------------------------------
// Pull-aggregate + mean (bf16 in / bf16 out, fp32 accum).
// Half-wave (32 lanes) per node, 8 nodes / 256-thread block.
// Neighbor ids prefetched lane-parallel then broadcast via __shfl so the
// X-row loads are independent (breaks the srcs->X dependent-latency chain).
// ---------------------------------------------------------------------------
__global__ __launch_bounds__(256) void k_gather_bf(
    const unsigned short* __restrict__ Xb, const int* __restrict__ srcs,
    const int* __restrict__ offs, const int* __restrict__ deg,
    unsigned short* __restrict__ outb, int N)
{
    int node = blockIdx.x * 8 + (threadIdx.x >> 5);
    if (node >= N) return;
    int lane  = threadIdx.x & 31;
    int start = offs[node];
    int d     = deg[node];
    float a0 = 0.f, a1 = 0.f, a2 = 0.f, a3 = 0.f;
    for (int base = 0; base < d; base += 32) {
        int cnt = min(d - base, 32);
        int sid = (lane < cnt) ? srcs[start + base + lane] : 0;
        for (int j = 0; j < cnt; ++j) {
            int s = __shfl(sid, j, 32);
            v4bf v = *(const v4bf*)(Xb + (size_t)s * NODE_D + lane * 4);
            a0 += (float)v[0]; a1 += (float)v[1];
            a2 += (float)v[2]; a3 += (float)v[3];
        }
    }
    float r = 1.0f / fmaxf((float)d, 1.0f);
    v4bf o;
    o[0] = (__bf16)(a0 * r); o[1] = (__bf16)(a1 * r);
    o[2] = (__bf16)(a2 * r); o[3] = (__bf16)(a3 * r);
    *(v4bf*)(outb + (size_t)node * NODE_D + lane * 4) = o;
}

// ---------------------------------------------------------------------------
// MFMA SAGE GEMM: out = maybe_relu([A0 || A1] @ W + bias).
// A0, A1 are bf16 [N][128]; Wt bf16 [128 cols][256 k] transposed.
// Block: 128 rows x 128 cols, 4 waves. out fp32 or bf16 per out_bf flag.
// ---------------------------------------------------------------------------
#define GROWS 128
#define GKC   64
#define GSTR  (GKC + 8)   // 72 bf16 rows -> <=2-way bank aliasing (free, m136)

__global__ __launch_bounds__(256) void k_gemm_mfma(
    const unsigned short* __restrict__ A0,    // [N][128] bf16 aggregate
    const unsigned short* __restrict__ A1,    // [N][128] bf16 x or h
    const unsigned short* __restrict__ Wt,    // [128][256] bf16 bits
    const float* __restrict__ bias,           // [128] fp32
    void* __restrict__ outp, int N, int do_relu, int out_bf)
{
    __shared__ __bf16 sA[GROWS][GSTR];
    __shared__ __bf16 sW[GROWS][GSTR];

    const int t    = threadIdx.x;
    const int wave = t >> 6;          // 0..3
    const int lane = t & 63;
    const int l15  = lane & 15;
    const int lg   = lane >> 4;       // 0..3
    const int row0 = blockIdx.x * GROWS;

    v4f acc[2][8];
#pragma unroll
    for (int m = 0; m < 2; ++m)
#pragma unroll
        for (int n = 0; n < 8; ++n)
            acc[m][n] = (v4f){0.f, 0.f, 0.f, 0.f};

    float bk[8];
#pragma unroll
    for (int n = 0; n < 8; ++n) bk[n] = bias[n * 16 + l15];

    for (int kc = 0; kc < 4; ++kc) {
        const int kbase = kc * GKC;                       // 0,64,128,192
        const unsigned short* Asrc = (kbase < NODE_D) ? A0 : A1;
        const int koff = kbase & (NODE_D - 1);            // 0 or 64
        // ---- stage A chunk: 128 rows x 64 k bf16. 4 x 16B per thread.
#pragma unroll
        for (int i = 0; i < 4; ++i) {
            int fi = i * 256 + t;     // 0..1023
            int r  = fi >> 3;         // 0..127
            int k8 = fi & 7;          // 0..7
            int row = row0 + r;
            v8bf v = (v8bf)(__bf16)0.f;
            if (row < N) v = *(const v8bf*)(Asrc + (size_t)row * NODE_D + koff + k8 * 8);
            *(v8bf*)&sA[r][k8 * 8] = v;
        }
        // ---- stage W chunk: 128 cols x 64 k bf16. 4 x 16B per thread.
#pragma unroll
        for (int i = 0; i < 4; ++i) {
            int fi = i * 256 + t;     // 0..1023
            int c  = fi >> 3;         // 0..127
            int k8 = fi & 7;          // 0..7
            v8bf w = *(const v8bf*)((const __bf16*)Wt + c * 256 + kbase + k8 * 8);
            *(v8bf*)&sW[c][k8 * 8] = w;
        }
        __syncthreads();
        // ---- compute: 2 k-steps of 32
#pragma unroll
        for (int ks = 0; ks < 2; ++ks) {
            const int kk = ks * 32 + lg * 8;
            v8bf a0 = *(const v8bf*)&sA[wave * 32 +  0 + l15][kk];
            v8bf a1 = *(const v8bf*)&sA[wave * 32 + 16 + l15][kk];
#pragma unroll
            for (int n = 0; n < 8; ++n) {
                v8bf b = *(const v8bf*)&sW[n * 16 + l15][kk];
                acc[0][n] = __builtin_amdgcn_mfma_f32_16x16x32_bf16(a0, b, acc[0][n], 0, 0, 0);
                acc[1][n] = __builtin_amdgcn_mfma_f32_16x16x32_bf16(a1, b, acc[1][n], 0, 0, 0);
            }
        }
        __syncthreads();
    }
    // ---- epilogue: bias + optional relu; fp32 or bf16 stores
    float* outf = (float*)outp;
    unsigned short* outh = (unsigned short*)outp;
#pragma unroll
    for (int m = 0; m < 2; ++m) {
#pragma unroll
        for (int rr = 0; rr < 4; ++rr) {
            int row = row0 + wave * 32 + m * 16 + lg * 4 + rr;
            if (row < N) {
#pragma unroll
                for (int n = 0; n < 8; ++n) {
                    float v = acc[m][n][rr] + bk[n];
                    if (do_relu) v = fmaxf(v, 0.f);
                    if (out_bf) {
                        __bf16 hb = (__bf16)v;
                        outh[(size_t)row * NODE_D + n * 16 + l15] =
                            __builtin_bit_cast(unsigned short, hb);
                    } else {
                        outf[(size_t)row * NODE_D + n * 16 + l15] = v;
                    }
                }
            }
        }
    }
}

// ---------------------------------------------------------------------------
// Global mean pool, phase 1: segment-sum by (sorted) batch id.
// ---------------------------------------------------------------------------
#define PR 256
__global__ __launch_bounds__(256) void k_pool(
    const float* __restrict__ Y, const int* __restrict__ batch,
    float* gsum, float* gcnt, int N)
{
    int col  = threadIdx.x & 127;
    int half = threadIdx.x >> 7;
    int r0   = blockIdx.x * PR;
    int rend = min(r0 + PR, N);
    float run = 0.f, rcount = 0.f;
    int cur = -1;
    for (int r = r0 + half; r < rend; r += 2) {
        int g = batch[r];
        if (g != cur) {
            if (cur >= 0) {
                atomicAdd(&gsum[cur * NODE_D + col], run);
                if (col == 0) atomicAdd(&gcnt[cur], rcount);
            }
            cur = g; run = 0.f; rcount = 0.f;
        }
        run    += Y[(size_t)r * NODE_D + col];
        rcount += 1.0f;
    }
    if (cur >= 0) {
        atomicAdd(&gsum[cur * NODE_D + col], run);
        if (col == 0) atomicAdd(&gcnt[cur], rcount);
    }
}

// ---------------------------------------------------------------------------
// Pool phase 2: out[g][j] = gsum[g][j] / max(gcnt[g],1)
// ---------------------------------------------------------------------------
__global__ __launch_bounds__(256) void k_finalize(
    const float* __restrict__ gsum, const float* __restrict__ gcnt, float* out)
{
    int idx = blockIdx.x * 256 + threadIdx.x;   // 0..8191
    int g = idx >> 7;
    out[idx] = gsum[idx] / fmaxf(gcnt[g], 1.0f);
}

// ---------------------------------------------------------------------------
extern "C" void kernel_launch(void* const* d_in, const int* in_sizes, int n_in,
                              void* d_out, int out_size, void* d_ws, size_t ws_size,
                              hipStream_t stream)
{
    const float* x   = (const float*)d_in[0];
    const int*   ei  = (const int*)d_in[1];
    const int*   bat = (const int*)d_in[2];
    const float* W1l = (const float*)d_in[3];
    const float* b1  = (const float*)d_in[4];
    const float* W1r = (const float*)d_in[5];
    const float* W2l = (const float*)d_in[6];
    const float* b2  = (const float*)d_in[7];
    const float* W2r = (const float*)d_in[8];

    const int N = in_sizes[0] / NODE_D;
    const int E = in_sizes[1] / 2;
    const int* srcp = ei;
    const int* dstp = ei + E;
    const int nb = (N + SCHUNK - 1) / SCHUNK;

    // workspace layout (bytes):
    //   [0,            N*512)  Y   fp32  (gemm2 out, pool in)
    //   [0,            N*256)  xb  bf16  — ALIASES Y; dead before gemm2 writes
    //   [N*512,        +N*256) Pb  bf16  (aggregate)
    //   [N*512+N*256,  +N*256) Qb  bf16  (h)
    //   then gsum/gcnt, deg, offs, cursor(+Wt overlay), partial, srcs
    char* wsb = (char*)d_ws;
    float* Y           = (float*)wsb;
    unsigned short* xb = (unsigned short*)wsb;
    unsigned short* Pb = (unsigned short*)(wsb + (size_t)N * 512);
    unsigned short* Qb = (unsigned short*)(wsb + (size_t)N * 512 + (size_t)N * 256);
    float* gsum = (float*)(wsb + (size_t)N * 512 + 2 * (size_t)N * 256);
    float* gcnt = gsum + NUM_GRAPHS * NODE_D;
    int* deg     = (int*)(gcnt + NUM_GRAPHS);         // [N]
    int* offs    = deg + N;                           // [N]
    int* cursor  = offs + N;                          // [N] (dead after k_fill)
    int* partial = cursor + N;                        // [nb]
    int* srcs    = partial + ((nb + 63) & ~63);       // [E]
    // Wt1/Wt2 (64KB each) overlay dead cursor (N ints = 400KB)
    unsigned short* Wt1 = (unsigned short*)cursor;
    unsigned short* Wt2 = Wt1 + 128 * 256;

    hipMemsetAsync(deg, 0, (size_t)N * sizeof(int), stream);
    hipMemsetAsync(gsum, 0, (NUM_GRAPHS * NODE_D + NUM_GRAPHS) * sizeof(float), stream);

    // ---- CSR build (once; shared by both layers)
    k_hist<<<(E + 255) / 256, 256, 0, stream>>>(dstp, deg, E);
    k_scan_partial<<<nb, 256, 0, stream>>>(deg, partial, N);
    k_scan_top<<<1, 64, 0, stream>>>(partial, nb);
    k_scan_final<<<nb, 256, 0, stream>>>(deg, partial, offs, cursor, N);
    k_fill<<<(E + 255) / 256, 256, 0, stream>>>(srcp, dstp, cursor, srcs, E);

    // ---- prep: weights (over dead cursor) + bf16 feature copy
    k_prep<<<128, 256, 0, stream>>>(W1l, W1r, Wt1);
    k_prep<<<128, 256, 0, stream>>>(W2l, W2r, Wt2);
    long n8 = (long)N * NODE_D / 8;
    k_prep_x<<<(int)((n8 + 255) / 256), 256, 0, stream>>>(x, xb, n8);

    const int gblk = (N + GROWS - 1) / GROWS;
    // ---- layer 1: mean-agg(xb) -> Pb, then h = relu([Pb||xb]W1) -> Qb (bf16)
    k_gather_bf<<<(N + 7) / 8, 256, 0, stream>>>(xb, srcs, offs, deg, Pb, N);
    k_gemm_mfma<<<gblk, 256, 0, stream>>>(Pb, xb, Wt1, b1, Qb, N, 1, 1);

    // ---- layer 2: mean-agg(Qb) -> Pb, then y = [Pb||Qb]W2 -> Y (fp32)
    k_gather_bf<<<(N + 7) / 8, 256, 0, stream>>>(Qb, srcs, offs, deg, Pb, N);
    k_gemm_mfma<<<gblk, 256, 0, stream>>>(Pb, Qb, Wt2, b2, Y, N, 0, 0);

    // ---- global mean pool
    k_pool<<<(N + PR - 1) / PR, 256, 0, stream>>>(Y, bat, gsum, gcnt, N);
    k_finalize<<<(NUM_GRAPHS * NODE_D) / 256, 256, 0, stream>>>(gsum, gcnt, (float*)d_out);
}

// Round 9
// 339.209 us; speedup vs baseline: 7.8943x; 1.0786x over previous
//
#include <hip/hip_runtime.h>

#define NODE_D 128
#define NUM_GRAPHS 64
#define SCHUNK 2048   // elements per scan block (256 thr x 8)

typedef __bf16 v8bf __attribute__((ext_vector_type(8)));
typedef __bf16 v4bf __attribute__((ext_vector_type(4)));
typedef float  v4f  __attribute__((ext_vector_type(4)));

// ---------------------------------------------------------------------------
// CSR build, step 1: degree histogram (int atomics — cheap)
// ---------------------------------------------------------------------------
__global__ __launch_bounds__(256) void k_hist(
    const int* __restrict__ dst, int* deg, int E)
{
    int e = blockIdx.x * 256 + threadIdx.x;
    if (e < E) atomicAdd(&deg[dst[e]], 1);
}

// ---------------------------------------------------------------------------
// CSR build, step 2a: per-block partial sums of deg
// ---------------------------------------------------------------------------
__global__ __launch_bounds__(256) void k_scan_partial(
    const int* __restrict__ deg, int* partial, int N)
{
    __shared__ int sbuf[256];
    int base = blockIdx.x * SCHUNK;
    int t = threadIdx.x;
    int s = 0;
#pragma unroll
    for (int i = 0; i < 8; ++i) {
        int idx = base + i * 256 + t;
        if (idx < N) s += deg[idx];
    }
    sbuf[t] = s;
    __syncthreads();
    for (int off = 128; off > 0; off >>= 1) {
        if (t < off) sbuf[t] += sbuf[t + off];
        __syncthreads();
    }
    if (t == 0) partial[blockIdx.x] = sbuf[0];
}

// ---------------------------------------------------------------------------
// CSR build, step 2b: serial exclusive scan of block partials (nb ~ 49)
// ---------------------------------------------------------------------------
__global__ void k_scan_top(int* partial, int nb)
{
    if (threadIdx.x == 0 && blockIdx.x == 0) {
        int run = 0;
        for (int i = 0; i < nb; ++i) { int v = partial[i]; partial[i] = run; run += v; }
    }
}

// ---------------------------------------------------------------------------
// CSR build, step 2c: per-block exclusive scan -> offs, cursor
// ---------------------------------------------------------------------------
__global__ __launch_bounds__(256) void k_scan_final(
    const int* __restrict__ deg, const int* __restrict__ partial,
    int* offs, int* cursor, int N)
{
    __shared__ int sbuf[256];
    int base = blockIdx.x * SCHUNK;
    int t = threadIdx.x;
    int idx0 = base + t * 8;
    int loc[8];
    int s = 0;
#pragma unroll
    for (int i = 0; i < 8; ++i) {
        int idx = idx0 + i;
        int v = (idx < N) ? deg[idx] : 0;
        loc[i] = s;
        s += v;
    }
    sbuf[t] = s;
    __syncthreads();
    for (int off = 1; off < 256; off <<= 1) {
        int tmp = (t >= off) ? sbuf[t - off] : 0;
        __syncthreads();
        sbuf[t] += tmp;
        __syncthreads();
    }
    int pre = sbuf[t] - s + partial[blockIdx.x];
#pragma unroll
    for (int i = 0; i < 8; ++i) {
        int idx = idx0 + i;
        if (idx < N) {
            int v = pre + loc[i];
            offs[idx]   = v;
            cursor[idx] = v;
        }
    }
}

// ---------------------------------------------------------------------------
// CSR build, step 3: bucket src ids into CSR order
// ---------------------------------------------------------------------------
__global__ __launch_bounds__(256) void k_fill(
    const int* __restrict__ src, const int* __restrict__ dst,
    int* cursor, int* srcs, int E)
{
    int e = blockIdx.x * 256 + threadIdx.x;
    if (e < E) {
        int pos = atomicAdd(&cursor[dst[e]], 1);
        srcs[pos] = src[e];
    }
}

// ---------------------------------------------------------------------------
// Graph bounds: gs[g] = first row of graph g (batch is sorted); gs[64] = N.
// Handles empty graphs (gs[g] = start of next non-empty graph).
// ---------------------------------------------------------------------------
__global__ __launch_bounds__(256) void k_bounds(
    const int* __restrict__ batch, int* __restrict__ gs, int N)
{
    int r = blockIdx.x * 256 + threadIdx.x;
    if (r >= N) return;
    if (r == 0) {
        for (int g = 0; g <= batch[0]; ++g) gs[g] = 0;
    } else {
        int b0 = batch[r - 1], b1 = batch[r];
        for (int g = b0 + 1; g <= b1; ++g) gs[g] = r;
    }
    if (r == N - 1) {
        for (int g = batch[N - 1] + 1; g <= NUM_GRAPHS; ++g) gs[g] = N;
    }
}

// ---------------------------------------------------------------------------
// Weight prep (both layers in one launch):
// Wt[c][k] = bf16( k<128 ? Wl[k][c] : Wr[k-128][c] )
// ---------------------------------------------------------------------------
__global__ __launch_bounds__(256) void k_prep2(
    const float* __restrict__ W1l, const float* __restrict__ W1r,
    const float* __restrict__ W2l, const float* __restrict__ W2r,
    unsigned short* __restrict__ Wt1, unsigned short* __restrict__ Wt2)
{
    int idx = blockIdx.x * 256 + threadIdx.x;   // 0..65535
    int which = idx >> 15;
    int i = idx & 32767;
    int k = i & 255;
    int c = i >> 8;
    const float* Wl = which ? W2l : W1l;
    const float* Wr = which ? W2r : W1r;
    unsigned short* Wt = which ? Wt2 : Wt1;
    float v = (k < 128) ? Wl[k * 128 + c] : Wr[(k - 128) * 128 + c];
    __bf16 b = (__bf16)v;
    Wt[c * 256 + k] = __builtin_bit_cast(unsigned short, b);
}

// ---------------------------------------------------------------------------
// Feature prep: xb = bf16(x), vectorized 8 elems/thread
// ---------------------------------------------------------------------------
__global__ __launch_bounds__(256) void k_prep_x(
    const float* __restrict__ x, unsigned short* __restrict__ xb, long n8)
{
    long idx = (long)blockIdx.x * 256 + threadIdx.x;   // over n8 = N*128/8
    if (idx >= n8) return;
    const float* p = x + idx * 8;
    float4 v0 = *(const float4*)p;
    float4 v1 = *(const float4*)(p + 4);
    v8bf b;
    b[0] = (__bf16)v0.x; b[1] = (__bf16)v0.y; b[2] = (__bf16)v0.z; b[3] = (__bf16)v0.w;
    b[4] = (__bf16)v1.x; b[5] = (__bf16)v1.y; b[6] = (__bf16)v1.z; b[7] = (__bf16)v1.w;
    *(v8bf*)(xb + idx * 8) = b;
}

// ---------------------------------------------------------------------------
// Pull-aggregate + mean (bf16 in / bf16 out, fp32 accum).
// Half-wave (32 lanes) per node, 8 nodes / 256-thread block.
// Neighbor ids prefetched lane-parallel then broadcast via __shfl.
// ---------------------------------------------------------------------------
__global__ __launch_bounds__(256) void k_gather_bf(
    const unsigned short* __restrict__ Xb, const int* __restrict__ srcs,
    const int* __restrict__ offs, const int* __restrict__ deg,
    unsigned short* __restrict__ outb, int N)
{
    int node = blockIdx.x * 8 + (threadIdx.x >> 5);
    if (node >= N) return;
    int lane  = threadIdx.x & 31;
    int start = offs[node];
    int d     = deg[node];
    float a0 = 0.f, a1 = 0.f, a2 = 0.f, a3 = 0.f;
    for (int base = 0; base < d; base += 32) {
        int cnt = min(d - base, 32);
        int sid = (lane < cnt) ? srcs[start + base + lane] : 0;
        for (int j = 0; j < cnt; ++j) {
            int s = __shfl(sid, j, 32);
            v4bf v = *(const v4bf*)(Xb + (size_t)s * NODE_D + lane * 4);
            a0 += (float)v[0]; a1 += (float)v[1];
            a2 += (float)v[2]; a3 += (float)v[3];
        }
    }
    float r = 1.0f / fmaxf((float)d, 1.0f);
    v4bf o;
    o[0] = (__bf16)(a0 * r); o[1] = (__bf16)(a1 * r);
    o[2] = (__bf16)(a2 * r); o[3] = (__bf16)(a3 * r);
    *(v4bf*)(outb + (size_t)node * NODE_D + lane * 4) = o;
}

// ---------------------------------------------------------------------------
// MFMA SAGE GEMM: out = maybe_relu([A0 || A1] @ W + bias).
// A0, A1 are bf16 [N][128]; Wt bf16 [128 cols][256 k] transposed.
// Block: 128 rows x 128 cols, 4 waves. out fp32 or bf16 per out_bf flag.
// ---------------------------------------------------------------------------
#define GROWS 128
#define GKC   64
#define GSTR  (GKC + 8)   // 72 bf16 rows -> <=2-way bank aliasing (free, m136)

__global__ __launch_bounds__(256) void k_gemm_mfma(
    const unsigned short* __restrict__ A0,    // [N][128] bf16 aggregate
    const unsigned short* __restrict__ A1,    // [N][128] bf16 x or h
    const unsigned short* __restrict__ Wt,    // [128][256] bf16 bits
    const float* __restrict__ bias,           // [128] fp32
    void* __restrict__ outp, int N, int do_relu, int out_bf)
{
    __shared__ __bf16 sA[GROWS][GSTR];
    __shared__ __bf16 sW[GROWS][GSTR];

    const int t    = threadIdx.x;
    const int wave = t >> 6;          // 0..3
    const int lane = t & 63;
    const int l15  = lane & 15;
    const int lg   = lane >> 4;       // 0..3
    const int row0 = blockIdx.x * GROWS;

    v4f acc[2][8];
#pragma unroll
    for (int m = 0; m < 2; ++m)
#pragma unroll
        for (int n = 0; n < 8; ++n)
            acc[m][n] = (v4f){0.f, 0.f, 0.f, 0.f};

    float bk[8];
#pragma unroll
    for (int n = 0; n < 8; ++n) bk[n] = bias[n * 16 + l15];

    for (int kc = 0; kc < 4; ++kc) {
        const int kbase = kc * GKC;                       // 0,64,128,192
        const unsigned short* Asrc = (kbase < NODE_D) ? A0 : A1;
        const int koff = kbase & (NODE_D - 1);            // 0 or 64
        // ---- stage A chunk: 128 rows x 64 k bf16. 4 x 16B per thread.
#pragma unroll
        for (int i = 0; i < 4; ++i) {
            int fi = i * 256 + t;     // 0..1023
            int r  = fi >> 3;         // 0..127
            int k8 = fi & 7;          // 0..7
            int row = row0 + r;
            v8bf v = (v8bf)(__bf16)0.f;
            if (row < N) v = *(const v8bf*)(Asrc + (size_t)row * NODE_D + koff + k8 * 8);
            *(v8bf*)&sA[r][k8 * 8] = v;
        }
        // ---- stage W chunk: 128 cols x 64 k bf16. 4 x 16B per thread.
#pragma unroll
        for (int i = 0; i < 4; ++i) {
            int fi = i * 256 + t;     // 0..1023
            int c  = fi >> 3;         // 0..127
            int k8 = fi & 7;          // 0..7
            v8bf w = *(const v8bf*)((const __bf16*)Wt + c * 256 + kbase + k8 * 8);
            *(v8bf*)&sW[c][k8 * 8] = w;
        }
        __syncthreads();
        // ---- compute: 2 k-steps of 32
#pragma unroll
        for (int ks = 0; ks < 2; ++ks) {
            const int kk = ks * 32 + lg * 8;
            v8bf a0 = *(const v8bf*)&sA[wave * 32 +  0 + l15][kk];
            v8bf a1 = *(const v8bf*)&sA[wave * 32 + 16 + l15][kk];
#pragma unroll
            for (int n = 0; n < 8; ++n) {
                v8bf b = *(const v8bf*)&sW[n * 16 + l15][kk];
                acc[0][n] = __builtin_amdgcn_mfma_f32_16x16x32_bf16(a0, b, acc[0][n], 0, 0, 0);
                acc[1][n] = __builtin_amdgcn_mfma_f32_16x16x32_bf16(a1, b, acc[1][n], 0, 0, 0);
            }
        }
        __syncthreads();
    }
    // ---- epilogue: bias + optional relu; fp32 or bf16 stores
    float* outf = (float*)outp;
    unsigned short* outh = (unsigned short*)outp;
#pragma unroll
    for (int m = 0; m < 2; ++m) {
#pragma unroll
        for (int rr = 0; rr < 4; ++rr) {
            int row = row0 + wave * 32 + m * 16 + lg * 4 + rr;
            if (row < N) {
#pragma unroll
                for (int n = 0; n < 8; ++n) {
                    float v = acc[m][n][rr] + bk[n];
                    if (do_relu) v = fmaxf(v, 0.f);
                    if (out_bf) {
                        __bf16 hb = (__bf16)v;
                        outh[(size_t)row * NODE_D + n * 16 + l15] =
                            __builtin_bit_cast(unsigned short, hb);
                    } else {
                        outf[(size_t)row * NODE_D + n * 16 + l15] = v;
                    }
                }
            }
        }
    }
}

// ---------------------------------------------------------------------------
// Global mean pool via graph bounds: grid (64 graphs x 16 splits).
// 32 row-lanes per block (2 halves x 16 splits); each lane strides by 32
// through the graph's contiguous rows. One atomic per thread at the end.
// ---------------------------------------------------------------------------
__global__ __launch_bounds__(256) void k_pool2(
    const float* __restrict__ Y, const int* __restrict__ gs,
    float* __restrict__ gsum)
{
    int g    = blockIdx.x;            // 0..63
    int s    = blockIdx.y;            // 0..15
    int col  = threadIdx.x & 127;
    int half = threadIdx.x >> 7;      // 0..1
    int r0 = gs[g], r1 = gs[g + 1];
    float run = 0.f;
    for (int r = r0 + s * 2 + half; r < r1; r += 32) {
        run += Y[(size_t)r * NODE_D + col];
    }
    atomicAdd(&gsum[g * NODE_D + col], run);
}

// ---------------------------------------------------------------------------
// Pool phase 2: out[g][j] = gsum[g][j] / max(gs[g+1]-gs[g], 1)
// ---------------------------------------------------------------------------
__global__ __launch_bounds__(256) void k_finalize(
    const float* __restrict__ gsum, const int* __restrict__ gs, float* out)
{
    int idx = blockIdx.x * 256 + threadIdx.x;   // 0..8191
    int g = idx >> 7;
    float cnt = (float)(gs[g + 1] - gs[g]);
    out[idx] = gsum[idx] / fmaxf(cnt, 1.0f);
}

// ---------------------------------------------------------------------------
extern "C" void kernel_launch(void* const* d_in, const int* in_sizes, int n_in,
                              void* d_out, int out_size, void* d_ws, size_t ws_size,
                              hipStream_t stream)
{
    const float* x   = (const float*)d_in[0];
    const int*   ei  = (const int*)d_in[1];
    const int*   bat = (const int*)d_in[2];
    const float* W1l = (const float*)d_in[3];
    const float* b1  = (const float*)d_in[4];
    const float* W1r = (const float*)d_in[5];
    const float* W2l = (const float*)d_in[6];
    const float* b2  = (const float*)d_in[7];
    const float* W2r = (const float*)d_in[8];

    const int N = in_sizes[0] / NODE_D;
    const int E = in_sizes[1] / 2;
    const int* srcp = ei;
    const int* dstp = ei + E;
    const int nb = (N + SCHUNK - 1) / SCHUNK;

    // workspace layout (bytes):
    //   [0,            N*512)  Y   fp32  (gemm2 out, pool in)
    //   [0,            N*256)  xb  bf16  — ALIASES Y; dead before gemm2 writes
    //   [N*512,        +N*256) Pb  bf16  (aggregate)
    //   [N*512+N*256,  +N*256) Qb  bf16  (h)
    //   then gsum, gs, deg, offs, cursor(+Wt overlay), partial, srcs
    char* wsb = (char*)d_ws;
    float* Y           = (float*)wsb;
    unsigned short* xb = (unsigned short*)wsb;
    unsigned short* Pb = (unsigned short*)(wsb + (size_t)N * 512);
    unsigned short* Qb = (unsigned short*)(wsb + (size_t)N * 512 + (size_t)N * 256);
    float* gsum = (float*)(wsb + (size_t)N * 512 + 2 * (size_t)N * 256);
    int* gs      = (int*)(gsum + NUM_GRAPHS * NODE_D); // [72] (65 used)
    int* deg     = gs + 72;                           // [N]
    int* offs    = deg + N;                           // [N]
    int* cursor  = offs + N;                          // [N] (dead after k_fill)
    int* partial = cursor + N;                        // [nb]
    int* srcs    = partial + ((nb + 63) & ~63);       // [E]
    // Wt1/Wt2 (64KB each) overlay dead cursor (N ints = 400KB)
    unsigned short* Wt1 = (unsigned short*)cursor;
    unsigned short* Wt2 = Wt1 + 128 * 256;

    hipMemsetAsync(deg, 0, (size_t)N * sizeof(int), stream);
    hipMemsetAsync(gsum, 0, NUM_GRAPHS * NODE_D * sizeof(float), stream);

    // ---- CSR build (once; shared by both layers) + graph bounds
    k_hist<<<(E + 255) / 256, 256, 0, stream>>>(dstp, deg, E);
    k_bounds<<<(N + 255) / 256, 256, 0, stream>>>(bat, gs, N);
    k_scan_partial<<<nb, 256, 0, stream>>>(deg, partial, N);
    k_scan_top<<<1, 64, 0, stream>>>(partial, nb);
    k_scan_final<<<nb, 256, 0, stream>>>(deg, partial, offs, cursor, N);
    k_fill<<<(E + 255) / 256, 256, 0, stream>>>(srcp, dstp, cursor, srcs, E);

    // ---- prep: weights (over dead cursor) + bf16 feature copy
    k_prep2<<<256, 256, 0, stream>>>(W1l, W1r, W2l, W2r, Wt1, Wt2);
    long n8 = (long)N * NODE_D / 8;
    k_prep_x<<<(int)((n8 + 255) / 256), 256, 0, stream>>>(x, xb, n8);

    const int gblk = (N + GROWS - 1) / GROWS;
    // ---- layer 1: mean-agg(xb) -> Pb, then h = relu([Pb||xb]W1) -> Qb (bf16)
    k_gather_bf<<<(N + 7) / 8, 256, 0, stream>>>(xb, srcs, offs, deg, Pb, N);
    k_gemm_mfma<<<gblk, 256, 0, stream>>>(Pb, xb, Wt1, b1, Qb, N, 1, 1);

    // ---- layer 2: mean-agg(Qb) -> Pb, then y = [Pb||Qb]W2 -> Y (fp32)
    k_gather_bf<<<(N + 7) / 8, 256, 0, stream>>>(Qb, srcs, offs, deg, Pb, N);
    k_gemm_mfma<<<gblk, 256, 0, stream>>>(Pb, Qb, Wt2, b2, Y, N, 0, 0);

    // ---- global mean pool (bounds-based, no per-row segment logic)
    dim3 pgrid(NUM_GRAPHS, 16);
    k_pool2<<<pgrid, 256, 0, stream>>>(Y, gs, gsum);
    k_finalize<<<(NUM_GRAPHS * NODE_D) / 256, 256, 0, stream>>>(gsum, gs, (float*)d_out);
}